// Round 6
// baseline (1551.770 us; speedup 1.0000x reference)
//
#include <hip/hip_runtime.h>
#include <hip/hip_fp16.h>

#define ND 56
#define HD 64
#define S1 60   // W1T row stride (words): [h=64][d=56 pad 60]
#define S2 68   // W2T row stride (words): [h=64][k=64 pad 68]
#define DEDD_H2 32  // dEdD row = 32 half2 = 64 halfs = 128B (56 used)

typedef float v4f __attribute__((ext_vector_type(4)));
typedef _Float16 v4h __attribute__((ext_vector_type(4)));

__global__ __launch_bounds__(256) void zero_kernel(float* __restrict__ p, int n) {
    int i = blockIdx.x * 256 + threadIdx.x;
    if (i < n) p[i] = 0.f;
}

// Persistent MLP fwd+bwd. One wave = 4 atoms (lane = hidden unit).
__global__ __launch_bounds__(256) void mlp_kernel(
    const float* __restrict__ x,        // [natoms*ND]
    const int*   __restrict__ indices,  // [natoms]
    const float* __restrict__ W1,       // [ND*HD]
    const float* __restrict__ b1,       // [HD]
    const float* __restrict__ W2,       // [HD*HD]
    const float* __restrict__ b2,       // [HD]
    const float* __restrict__ W3,       // [HD]
    const float* __restrict__ b3,       // [1]
    float* __restrict__ out_e,          // [nconf]
    __half2* __restrict__ dEdD,         // [natoms*DEDD_H2]
    int natoms)
{
    __shared__ float W1T[HD * S1 + 4];
    __shared__ float W2T[HD * S2];
    __shared__ float b1s[HD], b2s[HD], W3s[HD];
    __shared__ float xs[16 * ND];
    __shared__ float hbuf[4][4][HD];
    __shared__ float gbuf[4][4][HD];

    const int tid = threadIdx.x;
    for (int i = tid; i < ND * HD; i += 256) W1T[(i % HD) * S1 + (i / HD)] = W1[i];
    for (int i = tid; i < HD * HD; i += 256) W2T[(i % HD) * S2 + (i / HD)] = W2[i];
    if (tid < HD) { b1s[tid] = b1[tid]; b2s[tid] = b2[tid]; W3s[tid] = W3[tid]; }
    __syncthreads();

    const int w = tid >> 6, lane = tid & 63;
    const float b3v = b3[0];
    const float b1v = b1s[lane], b2v = b2s[lane], w3v = W3s[lane];
    const int nGroups = (natoms + 15) >> 4;

    for (int grp = blockIdx.x; grp < nGroups; grp += gridDim.x) {
        const int abase = grp * 16 + w * 4;

        if (lane < 56) {
            const int a = lane / 14;
            if (abase + a < natoms)
                reinterpret_cast<float4*>(xs + w * 4 * ND)[lane] =
                    reinterpret_cast<const float4*>(x)[(size_t)abase * 14 + lane];
        }

        float4 acc[4];
        // ---- fwd layer 1 ----
        #pragma unroll
        for (int a = 0; a < 4; ++a) acc[a] = float4{0.f, 0.f, 0.f, 0.f};
        #pragma unroll
        for (int i = 0; i < 14; ++i) {
            const float4 wv = *reinterpret_cast<const float4*>(&W1T[lane * S1 + 4 * i]);
            #pragma unroll
            for (int a = 0; a < 4; ++a) {
                const float4 xv = *reinterpret_cast<const float4*>(&xs[(w * 4 + a) * ND + 4 * i]);
                acc[a].x = fmaf(wv.x, xv.x, acc[a].x);
                acc[a].y = fmaf(wv.y, xv.y, acc[a].y);
                acc[a].z = fmaf(wv.z, xv.z, acc[a].z);
                acc[a].w = fmaf(wv.w, xv.w, acc[a].w);
            }
        }
        float z1[4], s1[4];
        #pragma unroll
        for (int a = 0; a < 4; ++a) {
            z1[a] = b1v + ((acc[a].x + acc[a].y) + (acc[a].z + acc[a].w));
            s1[a] = 1.f / (1.f + __expf(-z1[a]));
            hbuf[w][a][lane] = z1[a] * s1[a];
        }

        // ---- fwd layer 2 + energy + g2 ----
        #pragma unroll
        for (int a = 0; a < 4; ++a) acc[a] = float4{0.f, 0.f, 0.f, 0.f};
        #pragma unroll
        for (int i = 0; i < 16; ++i) {
            const float4 wv = *reinterpret_cast<const float4*>(&W2T[lane * S2 + 4 * i]);
            #pragma unroll
            for (int a = 0; a < 4; ++a) {
                const float4 hv = *reinterpret_cast<const float4*>(&hbuf[w][a][4 * i]);
                acc[a].x = fmaf(wv.x, hv.x, acc[a].x);
                acc[a].y = fmaf(wv.y, hv.y, acc[a].y);
                acc[a].z = fmaf(wv.z, hv.z, acc[a].z);
                acc[a].w = fmaf(wv.w, hv.w, acc[a].w);
            }
        }
        float ev[4];
        #pragma unroll
        for (int a = 0; a < 4; ++a) {
            const float z2 = b2v + ((acc[a].x + acc[a].y) + (acc[a].z + acc[a].w));
            const float s2 = 1.f / (1.f + __expf(-z2));
            ev[a] = (z2 * s2) * w3v;
            gbuf[w][a][lane] = w3v * (s2 * (1.f + z2 * (1.f - s2)));
        }
        #pragma unroll
        for (int off = 32; off > 0; off >>= 1) {
            #pragma unroll
            for (int a = 0; a < 4; ++a) ev[a] += __shfl_xor(ev[a], off);
        }
        if (lane == 0) {
            #pragma unroll
            for (int a = 0; a < 4; ++a)
                if (abase + a < natoms)
                    unsafeAtomicAdd(&out_e[indices[abase + a]], ev[a] + b3v);
        }

        // ---- bwd: dh1 -> g1 ----
        #pragma unroll
        for (int a = 0; a < 4; ++a) acc[a] = float4{0.f, 0.f, 0.f, 0.f};
        #pragma unroll
        for (int i = 0; i < 16; ++i) {
            const float w0 = W2T[(4 * i + 0) * S2 + lane];
            const float w1v = W2T[(4 * i + 1) * S2 + lane];
            const float w2v = W2T[(4 * i + 2) * S2 + lane];
            const float w3x = W2T[(4 * i + 3) * S2 + lane];
            #pragma unroll
            for (int a = 0; a < 4; ++a) {
                const float4 gv = *reinterpret_cast<const float4*>(&gbuf[w][a][4 * i]);
                acc[a].x = fmaf(w0, gv.x, acc[a].x);
                acc[a].y = fmaf(w1v, gv.y, acc[a].y);
                acc[a].z = fmaf(w2v, gv.z, acc[a].z);
                acc[a].w = fmaf(w3x, gv.w, acc[a].w);
            }
        }
        #pragma unroll
        for (int a = 0; a < 4; ++a) {
            const float dh1 = (acc[a].x + acc[a].y) + (acc[a].z + acc[a].w);
            hbuf[w][a][lane] = dh1 * (s1[a] * (1.f + z1[a] * (1.f - s1[a])));
        }

        // ---- bwd: dx ----
        #pragma unroll
        for (int a = 0; a < 4; ++a) acc[a] = float4{0.f, 0.f, 0.f, 0.f};
        #pragma unroll
        for (int i = 0; i < 16; ++i) {
            const float w0 = W1T[(4 * i + 0) * S1 + lane];
            const float w1v = W1T[(4 * i + 1) * S1 + lane];
            const float w2v = W1T[(4 * i + 2) * S1 + lane];
            const float w3x = W1T[(4 * i + 3) * S1 + lane];
            #pragma unroll
            for (int a = 0; a < 4; ++a) {
                const float4 gv = *reinterpret_cast<const float4*>(&hbuf[w][a][4 * i]);
                acc[a].x = fmaf(w0, gv.x, acc[a].x);
                acc[a].y = fmaf(w1v, gv.y, acc[a].y);
                acc[a].z = fmaf(w2v, gv.z, acc[a].z);
                acc[a].w = fmaf(w3x, gv.w, acc[a].w);
            }
        }
        // pack fp16 pairs: even lane stores {v[lane], v[lane+1]} as __half2
        #pragma unroll
        for (int a = 0; a < 4; ++a) {
            const float v  = (acc[a].x + acc[a].y) + (acc[a].z + acc[a].w);
            const float vh = __shfl_down(v, 1);
            if ((lane & 1) == 0 && lane < ND && abase + a < natoms)
                dEdD[(size_t)(abase + a) * DEDD_H2 + (lane >> 1)] =
                    __floats2half2_rn(v, vh);
        }
    }
}

// Fused force kernel: 16 lanes per derivative row.
__global__ __launch_bounds__(256) void force_kernel(
    const float* __restrict__ xd,       // [M*ND]
    const int*   __restrict__ xd_indx,  // [M*3]
    const int*   __restrict__ unique_j, // [M]
    const _Float16* __restrict__ dEdD,  // [natoms*64] halfs
    float* __restrict__ out_f,          // [3*natoms]
    int M)
{
    const long t = (long)blockIdx.x * 256 + threadIdx.x;
    const int  m   = (int)(t >> 4);
    const int  sub = (int)(t & 15);

    float partial = 0.f;
    if (m < M) {
        const int a = __builtin_nontemporal_load(xd_indx + 3 * (size_t)m);
        if (sub < 14) {
            const v4f u = __builtin_nontemporal_load(
                reinterpret_cast<const v4f*>(xd) + (size_t)m * 14 + sub);
            const v4h hv = reinterpret_cast<const v4h*>(dEdD + ((size_t)a << 6))[sub];
            partial = fmaf(u.x, (float)hv.x,
                      fmaf(u.y, (float)hv.y,
                      fmaf(u.z, (float)hv.z, u.w * (float)hv.w)));
        }
    }
    partial += __shfl_xor(partial, 1);
    partial += __shfl_xor(partial, 2);
    partial += __shfl_xor(partial, 4);
    partial += __shfl_xor(partial, 8);

    if (m < M && sub == 0) {
        const int coord = __builtin_nontemporal_load(xd_indx + 3 * (size_t)m + 2);
        const int j     = __builtin_nontemporal_load(unique_j + m);
        unsafeAtomicAdd(&out_f[(size_t)j * 3 + coord], partial);
    }
}

extern "C" void kernel_launch(void* const* d_in, const int* in_sizes, int n_in,
                              void* d_out, int out_size, void* d_ws, size_t ws_size,
                              hipStream_t stream) {
    const float* x        = (const float*)d_in[0];
    const float* xd       = (const float*)d_in[1];
    const int*   indices  = (const int*)d_in[2];
    const int*   xd_indx  = (const int*)d_in[4];
    const int*   unique_j = (const int*)d_in[5];
    const float* W1 = (const float*)d_in[6];
    const float* b1 = (const float*)d_in[7];
    const float* W2 = (const float*)d_in[8];
    const float* b2 = (const float*)d_in[9];
    const float* W3 = (const float*)d_in[10];
    const float* b3 = (const float*)d_in[11];

    const int natoms = in_sizes[0] / ND;
    const int M      = in_sizes[1] / ND;
    const int nconf  = in_sizes[3];

    float*    out_e  = (float*)d_out;          // [nconf]
    float*    out_f  = out_e + nconf;          // [3*natoms]
    __half2*  dEdD2  = (__half2*)d_ws;         // [natoms*32] half2 (6.4 MB)
    _Float16* dEdDh  = (_Float16*)d_ws;

    // ---- ATTRIBUTION DUMMIES (outputs -> far scratch; timing-identical) ----
    // dur_r6 - dur_r5 = 3*t_mlp + 1*t_force
    __half2*  dumDeD2 = (__half2*)((char*)d_ws + (64u << 20));   // +64MB
    _Float16* dumDeDh = (_Float16*)((char*)d_ws + (64u << 20));
    float*    dumOut  = (float*)((char*)d_ws + (128u << 20));    // +128MB (out_e+out_f sized)

    const int nGroups = (natoms + 15) >> 4;
    const int mlpGrid = nGroups < 768 ? nGroups : 768;
    const long fthreads = (long)M * 16;
    const unsigned fGrid = (unsigned)((fthreads + 255) / 256);

    for (int r = 0; r < 3; ++r)
        mlp_kernel<<<mlpGrid, 256, 0, stream>>>(
            x, indices, W1, b1, W2, b2, W3, b3, dumOut, dumDeD2, natoms);
    force_kernel<<<fGrid, 256, 0, stream>>>(
        xd, xd_indx, unique_j, dumDeDh, dumOut + nconf, M);

    // ---- real sequence (identical to round 5) ----
    zero_kernel<<<(out_size + 255) / 256, 256, 0, stream>>>((float*)d_out, out_size);

    mlp_kernel<<<mlpGrid, 256, 0, stream>>>(
        x, indices, W1, b1, W2, b2, W3, b3, out_e, dEdD2, natoms);

    force_kernel<<<fGrid, 256, 0, stream>>>(
        xd, xd_indx, unique_j, dEdDh, out_f, M);
}

// Round 7
// 532.573 us; speedup vs baseline: 2.9137x; 2.9137x over previous
//
#include <hip/hip_runtime.h>
#include <hip/hip_fp16.h>

#define ND 56
#define HD 64
#define DEDD_H2 32  // dEdD row = 32 half2 = 64 halfs = 128B (56 used)

typedef float v4f __attribute__((ext_vector_type(4)));
typedef _Float16 v4h __attribute__((ext_vector_type(4)));

__global__ __launch_bounds__(256) void zero_kernel(float* __restrict__ p, int n) {
    int i = blockIdx.x * 256 + threadIdx.x;
    if (i < n) p[i] = 0.f;
}

// Persistent MLP fwd+bwd. One wave = 4 atoms (lane = hidden unit).
// v7: unroll-capped bodies (kill spill/I$), rows padded to 64 + slot-XOR
// iteration (bank-optimal b128 reads), broadcast x/h reads.
__global__ __launch_bounds__(256) void mlp_kernel(
    const float* __restrict__ x,        // [natoms*ND]
    const int*   __restrict__ indices,  // [natoms]
    const float* __restrict__ W1,       // [ND*HD]
    const float* __restrict__ b1,       // [HD]
    const float* __restrict__ W2,       // [HD*HD]
    const float* __restrict__ b2,       // [HD]
    const float* __restrict__ W3,       // [HD]
    const float* __restrict__ b3,       // [1]
    float* __restrict__ out_e,          // [nconf]
    __half2* __restrict__ dEdD,         // [natoms*DEDD_H2]
    int natoms)
{
    __shared__ float W1R[HD * 64];      // [h][d], d padded 56->64 with zeros
    __shared__ float W2R[HD * 64];      // [h][k] = W2[k][h]
    __shared__ float b1s[HD], b2s[HD], W3s[HD];
    __shared__ float xs[16][64];        // padded atom rows (zeros in 56..63)
    __shared__ float hbuf[4][4][HD];    // wave, atom, unit (h1, later g1)
    __shared__ float gbuf[4][4][HD];    // wave, atom, unit (g2)

    const int tid = threadIdx.x;
    // coalesced global reads; one-time scattered LDS writes
    for (int i = tid; i < ND * HD; i += 256) {          // W1[d][h] -> W1R[h][d]
        const int d = i >> 6, h = i & 63;
        W1R[h * 64 + d] = W1[i];
    }
    for (int i = tid; i < HD * 8; i += 256) {           // zero the d-pad
        const int h = i >> 3, d = 56 + (i & 7);
        W1R[h * 64 + d] = 0.f;
    }
    for (int i = tid; i < HD * HD; i += 256) {          // W2[k][h] -> W2R[h][k]
        const int k = i >> 6, h = i & 63;
        W2R[h * 64 + k] = W2[i];
    }
    if (tid < HD) { b1s[tid] = b1[tid]; b2s[tid] = b2[tid]; W3s[tid] = W3[tid]; }
    __syncthreads();

    const int w = tid >> 6, lane = tid & 63;
    const int l15 = lane & 15;
    const float b3v = b3[0];
    const float b1v = b1s[lane], b2v = b2s[lane], w3v = W3s[lane];
    const int nGroups = (natoms + 15) >> 4;

    for (int grp = blockIdx.x; grp < nGroups; grp += gridDim.x) {
        const int abase = grp * 16 + w * 4;   // this wave's 4 atoms

        // stage 4 atoms, padded with zeros (wave-private; no barrier needed)
        {
            const int ai   = lane >> 4;       // 0..3
            const int slot = lane & 15;       // 0..15
            const int atom = abase + ai;
            float4 val = float4{0.f, 0.f, 0.f, 0.f};
            if (slot < 14 && atom < natoms)
                val = reinterpret_cast<const float4*>(x)[(size_t)atom * 14 + slot];
            *reinterpret_cast<float4*>(&xs[w * 4 + ai][4 * slot]) = val;
        }

        float4 acc[4];
        // ---- fwd layer 1: z1[h=lane] ----
        #pragma unroll
        for (int a = 0; a < 4; ++a) acc[a] = float4{0.f, 0.f, 0.f, 0.f};
        #pragma unroll 2
        for (int s = 0; s < 16; ++s) {
            const int slot = s ^ l15;
            const float4 wv = *reinterpret_cast<const float4*>(&W1R[lane * 64 + 4 * slot]);
            #pragma unroll
            for (int a = 0; a < 4; ++a) {
                const float4 xv = *reinterpret_cast<const float4*>(&xs[w * 4 + a][4 * slot]);
                acc[a].x = fmaf(wv.x, xv.x, acc[a].x);
                acc[a].y = fmaf(wv.y, xv.y, acc[a].y);
                acc[a].z = fmaf(wv.z, xv.z, acc[a].z);
                acc[a].w = fmaf(wv.w, xv.w, acc[a].w);
            }
        }
        float z1[4], s1[4];
        #pragma unroll
        for (int a = 0; a < 4; ++a) {
            z1[a] = b1v + ((acc[a].x + acc[a].y) + (acc[a].z + acc[a].w));
            s1[a] = 1.f / (1.f + __expf(-z1[a]));
            hbuf[w][a][lane] = z1[a] * s1[a];
        }

        // ---- fwd layer 2 + energy + g2 ----
        #pragma unroll
        for (int a = 0; a < 4; ++a) acc[a] = float4{0.f, 0.f, 0.f, 0.f};
        #pragma unroll 2
        for (int s = 0; s < 16; ++s) {
            const int slot = s ^ l15;
            const float4 wv = *reinterpret_cast<const float4*>(&W2R[lane * 64 + 4 * slot]);
            #pragma unroll
            for (int a = 0; a < 4; ++a) {
                const float4 hv = *reinterpret_cast<const float4*>(&hbuf[w][a][4 * slot]);
                acc[a].x = fmaf(wv.x, hv.x, acc[a].x);
                acc[a].y = fmaf(wv.y, hv.y, acc[a].y);
                acc[a].z = fmaf(wv.z, hv.z, acc[a].z);
                acc[a].w = fmaf(wv.w, hv.w, acc[a].w);
            }
        }
        float ev[4];
        #pragma unroll
        for (int a = 0; a < 4; ++a) {
            const float z2 = b2v + ((acc[a].x + acc[a].y) + (acc[a].z + acc[a].w));
            const float s2 = 1.f / (1.f + __expf(-z2));
            ev[a] = (z2 * s2) * w3v;
            gbuf[w][a][lane] = w3v * (s2 * (1.f + z2 * (1.f - s2)));
        }
        #pragma unroll
        for (int off = 32; off > 0; off >>= 1) {
            #pragma unroll
            for (int a = 0; a < 4; ++a) ev[a] += __shfl_xor(ev[a], off);
        }
        if (lane == 0) {
            #pragma unroll
            for (int a = 0; a < 4; ++a)
                if (abase + a < natoms)
                    unsafeAtomicAdd(&out_e[indices[abase + a]], ev[a] + b3v);
        }

        // ---- bwd: dh1 (lane = k) -> g1 ----
        #pragma unroll
        for (int a = 0; a < 4; ++a) acc[a] = float4{0.f, 0.f, 0.f, 0.f};
        #pragma unroll 2
        for (int i = 0; i < 16; ++i) {
            const float w0  = W2R[(4 * i + 0) * 64 + lane];
            const float w1v = W2R[(4 * i + 1) * 64 + lane];
            const float w2v = W2R[(4 * i + 2) * 64 + lane];
            const float w3x = W2R[(4 * i + 3) * 64 + lane];
            #pragma unroll
            for (int a = 0; a < 4; ++a) {
                const float4 gv = *reinterpret_cast<const float4*>(&gbuf[w][a][4 * i]);
                acc[a].x = fmaf(w0,  gv.x, acc[a].x);
                acc[a].y = fmaf(w1v, gv.y, acc[a].y);
                acc[a].z = fmaf(w2v, gv.z, acc[a].z);
                acc[a].w = fmaf(w3x, gv.w, acc[a].w);
            }
        }
        #pragma unroll
        for (int a = 0; a < 4; ++a) {
            const float dh1 = (acc[a].x + acc[a].y) + (acc[a].z + acc[a].w);
            hbuf[w][a][lane] = dh1 * (s1[a] * (1.f + z1[a] * (1.f - s1[a])));  // g1
        }

        // ---- bwd: dx (lane = d) ----
        #pragma unroll
        for (int a = 0; a < 4; ++a) acc[a] = float4{0.f, 0.f, 0.f, 0.f};
        #pragma unroll 2
        for (int i = 0; i < 16; ++i) {
            const float w0  = W1R[(4 * i + 0) * 64 + lane];
            const float w1v = W1R[(4 * i + 1) * 64 + lane];
            const float w2v = W1R[(4 * i + 2) * 64 + lane];
            const float w3x = W1R[(4 * i + 3) * 64 + lane];
            #pragma unroll
            for (int a = 0; a < 4; ++a) {
                const float4 gv = *reinterpret_cast<const float4*>(&hbuf[w][a][4 * i]);
                acc[a].x = fmaf(w0,  gv.x, acc[a].x);
                acc[a].y = fmaf(w1v, gv.y, acc[a].y);
                acc[a].z = fmaf(w2v, gv.z, acc[a].z);
                acc[a].w = fmaf(w3x, gv.w, acc[a].w);
            }
        }
        // pack fp16 pairs: even lane stores {v[lane], v[lane+1]}
        #pragma unroll
        for (int a = 0; a < 4; ++a) {
            const float v  = (acc[a].x + acc[a].y) + (acc[a].z + acc[a].w);
            const float vh = __shfl_down(v, 1);
            if ((lane & 1) == 0 && lane < ND && abase + a < natoms)
                dEdD[(size_t)(abase + a) * DEDD_H2 + (lane >> 1)] =
                    __floats2half2_rn(v, vh);
        }
    }
}

// Fused force kernel: 16 lanes per derivative row (identical to round 5).
__global__ __launch_bounds__(256) void force_kernel(
    const float* __restrict__ xd,       // [M*ND]
    const int*   __restrict__ xd_indx,  // [M*3]
    const int*   __restrict__ unique_j, // [M]
    const _Float16* __restrict__ dEdD,  // [natoms*64] halfs
    float* __restrict__ out_f,          // [3*natoms]
    int M)
{
    const long t = (long)blockIdx.x * 256 + threadIdx.x;
    const int  m   = (int)(t >> 4);
    const int  sub = (int)(t & 15);

    float partial = 0.f;
    if (m < M) {
        const int a = __builtin_nontemporal_load(xd_indx + 3 * (size_t)m);
        if (sub < 14) {
            const v4f u = __builtin_nontemporal_load(
                reinterpret_cast<const v4f*>(xd) + (size_t)m * 14 + sub);
            const v4h hv = reinterpret_cast<const v4h*>(dEdD + ((size_t)a << 6))[sub];
            partial = fmaf(u.x, (float)hv.x,
                      fmaf(u.y, (float)hv.y,
                      fmaf(u.z, (float)hv.z, u.w * (float)hv.w)));
        }
    }
    partial += __shfl_xor(partial, 1);
    partial += __shfl_xor(partial, 2);
    partial += __shfl_xor(partial, 4);
    partial += __shfl_xor(partial, 8);

    if (m < M && sub == 0) {
        const int coord = __builtin_nontemporal_load(xd_indx + 3 * (size_t)m + 2);
        const int j     = __builtin_nontemporal_load(unique_j + m);
        unsafeAtomicAdd(&out_f[(size_t)j * 3 + coord], partial);
    }
}

extern "C" void kernel_launch(void* const* d_in, const int* in_sizes, int n_in,
                              void* d_out, int out_size, void* d_ws, size_t ws_size,
                              hipStream_t stream) {
    const float* x        = (const float*)d_in[0];
    const float* xd       = (const float*)d_in[1];
    const int*   indices  = (const int*)d_in[2];
    const int*   xd_indx  = (const int*)d_in[4];
    const int*   unique_j = (const int*)d_in[5];
    const float* W1 = (const float*)d_in[6];
    const float* b1 = (const float*)d_in[7];
    const float* W2 = (const float*)d_in[8];
    const float* b2 = (const float*)d_in[9];
    const float* W3 = (const float*)d_in[10];
    const float* b3 = (const float*)d_in[11];

    const int natoms = in_sizes[0] / ND;
    const int M      = in_sizes[1] / ND;
    const int nconf  = in_sizes[3];

    float*    out_e  = (float*)d_out;          // [nconf]
    float*    out_f  = out_e + nconf;          // [3*natoms]
    __half2*  dEdD2  = (__half2*)d_ws;         // [natoms*32] half2 (6.4 MB)
    _Float16* dEdDh  = (_Float16*)d_ws;

    zero_kernel<<<(out_size + 255) / 256, 256, 0, stream>>>((float*)d_out, out_size);

    const int nGroups = (natoms + 15) >> 4;
    const int mlpGrid = nGroups < 768 ? nGroups : 768;   // 3 blocks/CU (45KB LDS)
    mlp_kernel<<<mlpGrid, 256, 0, stream>>>(
        x, indices, W1, b1, W2, b2, W3, b3, out_e, dEdD2, natoms);

    const long fthreads = (long)M * 16;
    force_kernel<<<(unsigned)((fthreads + 255) / 256), 256, 0, stream>>>(
        xd, xd_indx, unique_j, dEdDh, out_f, M);
}